// Round 9
// baseline (473.812 us; speedup 1.0000x reference)
//
#include <hip/hip_runtime.h>

#define CH 256
#define HH 56
#define WW 56
#define HWSZ 3136
#define WQ_ELEMS (CH*CH*9)      // 589824

#define XROW 2048               // shorts: 64 iw * 32 ic
#define XBUF (4*XROW)           // 4 input row planes = 8192 shorts = 16 KB

typedef short short8 __attribute__((ext_vector_type(8)));
typedef float f32x4 __attribute__((ext_vector_type(4)));

__device__ __forceinline__ unsigned short f2bf(float f) {
  unsigned u = __builtin_bit_cast(unsigned, f);
  u += 0x7FFFu + ((u >> 16) & 1u);   // round-to-nearest-even
  return (unsigned short)(u >> 16);
}

// ---------------- kernel 1: max(|w|) ----------------
__global__ void absmax_kernel(const float4* __restrict__ w, unsigned* __restrict__ out) {
  int tid = blockIdx.x * 256 + threadIdx.x;
  float4 v = w[tid];
  float m = fmaxf(fmaxf(fabsf(v.x), fabsf(v.y)), fmaxf(fabsf(v.z), fabsf(v.w)));
  #pragma unroll
  for (int o = 32; o; o >>= 1) m = fmaxf(m, __shfl_xor(m, o, 64));
  if ((threadIdx.x & 63) == 0) atomicMax(out, __builtin_bit_cast(unsigned, m));
}

// ---------------- kernel 2: quantize -> bf16, layout [tap][ic-chunk][oc][32ic] ----------------
// offset = tap*65536 + t*8192 + oc*32 + ic2 : A-loads are 1KB fully-coalesced per wave.
__global__ void quant_kernel(const float* __restrict__ w, const float* __restrict__ Wp,
                             const float* __restrict__ Wn, const unsigned* __restrict__ mx,
                             unsigned short* __restrict__ wq) {
  int o = blockIdx.x * 256 + threadIdx.x;
  int ic2 = o & 31, oc = (o >> 5) & 255, t = (o >> 13) & 7, tap = o >> 16;
  int ic = t * 32 + ic2;
  float m = __builtin_bit_cast(float, *mx);
  float thr = 0.05f * m;
  float v = w[(oc * CH + ic) * 9 + tap];
  float q = 0.f;
  if (m > 0.f) {
    if (v > thr) q = Wp[0];
    else if (v < -thr) q = -Wn[0];
  }
  wq[o] = f2bf(q);
}

// ---------------- kernel 3: conv ----------------
// Block = (n, 2 output rows), 256 thr = 4 waves = 2 oc-halves x 2 rows.
// Wave tile 128oc x 64w x 1 row (acc=128). 2 blocks/CU: sibling block provides
// the latency-hiding TLP (no intra-block software pipeline needed).
// A (weights) read straight from global (L1/L2-resident, coalesced, reg-dbuf per tap).
// X in LDS, dbuf per ic-chunk, zero-conflict swizzle (measured R4). 2 barriers per chunk.
__global__ __launch_bounds__(256, 2)
void conv_kernel(const float* __restrict__ x, const unsigned short* __restrict__ wq,
                 const float* __restrict__ bias, float* __restrict__ out) {
  __shared__ __align__(16) unsigned short Xl[2 * XBUF];   // 32 KB

  const int tid  = threadIdx.x;
  const int lane = tid & 63;
  const int l15  = lane & 15;
  const int kg   = lane >> 4;      // 0..3 (ic octet)
  const int wid  = tid >> 6;       // 0..3
  const int och  = wid & 1;        // oc half (128 oc)
  const int wrp  = wid >> 1;       // output row 0..1
  const int n    = blockIdx.x;
  const int h0   = blockIdx.y * 2;

  f32x4 acc[8][4];
  #pragma unroll
  for (int m = 0; m < 8; ++m)
    #pragma unroll
    for (int nc = 0; nc < 4; ++nc) acc[m][nc] = (f32x4)0.f;

  // ---- X staging geometry: 1024 chunks (r, iw, slot), 4/thread; iw fastest -> coalesced ----
  int goff[4], loff[4];
  bool ok[4];
  #pragma unroll
  for (int k = 0; k < 4; ++k) {
    int c    = tid + k * 256;
    int iw   = c & 63;
    int slot = (c >> 6) & 3;
    int r    = c >> 8;             // 0..3
    int hx = h0 + r - 1;
    int xw = iw - 1;
    ok[k] = ((unsigned)hx < (unsigned)HH) && ((unsigned)xw < (unsigned)WW);
    goff[k] = slot * 8 * HWSZ + (ok[k] ? (hx * WW + xw) : 0);
    loff[k] = r * XROW + iw * 32 + ((slot ^ ((iw >> 1) & 3)) * 8);
  }
  const float* xbase = x + (long)n * CH * HWSZ;

  // ---- B-read offsets (zero-conflict swizzle, measured in R4) ----
  int boff[12];
  #pragma unroll
  for (int kw = 0; kw < 3; ++kw)
    #pragma unroll
    for (int nc = 0; nc < 4; ++nc) {
      int iw = nc * 16 + l15 + kw;
      if (iw > 63) iw = 63;        // feeds only discarded w >= 56
      boff[kw * 4 + nc] = iw * 32 + ((kg ^ ((iw >> 1) & 3)) * 8);
    }

  const unsigned short* abase = wq + (och * 128 + l15) * 32 + kg * 8;

  float xr[4][8];
  auto loadX = [&](int t) {
    #pragma unroll
    for (int k = 0; k < 4; ++k)
      #pragma unroll
      for (int j = 0; j < 8; ++j)
        xr[k][j] = xbase[goff[k] + (t * 32 + j) * HWSZ];
  };
  auto writeX = [&](int buf) {
    #pragma unroll
    for (int k = 0; k < 4; ++k) {
      short8 p;
      #pragma unroll
      for (int j = 0; j < 8; ++j) p[j] = ok[k] ? (short)f2bf(xr[k][j]) : (short)0;
      *(short8*)&Xl[buf + loff[k]] = p;
    }
  };

  // ---- prologue ----
  loadX(0);
  writeX(0);
  __syncthreads();

  for (int t = 0; t < 8; ++t) {
    const int cur = (t & 1) * XBUF;
    const int nxt = XBUF - cur;
    const unsigned short* aq = abase + t * 8192;

    if (t < 7) loadX(t + 1);       // issue early; consumed mid-compute

    // ---- 9 taps, A register-dbuf (one-tap lookahead), B from LDS ----
    short8 a[2][8];
    #pragma unroll
    for (int m = 0; m < 8; ++m) a[0][m] = *(const short8*)(aq + m * 512);
    #pragma unroll
    for (int s = 0; s < 9; ++s) {          // s = kh*3+kw = tap
      const int kh = s / 3, kw = s % 3, pb = s & 1;
      if (s < 8) {
        const unsigned short* an = aq + (s + 1) * 65536;
        #pragma unroll
        for (int m = 0; m < 8; ++m) a[pb ^ 1][m] = *(const short8*)(an + m * 512);
      }
      const int rxo = cur + (wrp + kh) * XROW;
      short8 b[4];
      #pragma unroll
      for (int nc = 0; nc < 4; ++nc) b[nc] = *(const short8*)&Xl[rxo + boff[kw * 4 + nc]];
      __builtin_amdgcn_s_setprio(1);
      #pragma unroll
      for (int m = 0; m < 8; ++m)
        #pragma unroll
        for (int nc = 0; nc < 4; ++nc)
          acc[m][nc] = __builtin_amdgcn_mfma_f32_16x16x32_bf16(a[pb][m], b[nc], acc[m][nc], 0, 0, 0);
      __builtin_amdgcn_s_setprio(0);

      // mid-compute: drain X loads + write to the free buffer (4 taps of cover each side)
      if (s == 4 && t < 7) writeX(nxt);
    }
    __syncthreads();
  }

  // ---- epilogue: D col = l15 (w), row = kg*4 + j (oc) ----
  const int h = h0 + wrp;
  #pragma unroll
  for (int m = 0; m < 8; ++m) {
    const int ocb = och * 128 + m * 16 + kg * 4;
    #pragma unroll
    for (int nc = 0; nc < 4; ++nc) {
      const int w = nc * 16 + l15;
      if (w < WW) {
        float* op = out + ((long)(n * CH + ocb) * HH + h) * WW + w;
        #pragma unroll
        for (int j = 0; j < 4; ++j)
          op[(long)j * HWSZ] = acc[m][nc][j] + bias[ocb + j];
      }
    }
  }
}

extern "C" void kernel_launch(void* const* d_in, const int* in_sizes, int n_in,
                              void* d_out, int out_size, void* d_ws, size_t ws_size,
                              hipStream_t stream) {
  const float* x      = (const float*)d_in[0];
  const float* weight = (const float*)d_in[1];
  const float* bias   = (const float*)d_in[2];
  const float* Wp     = (const float*)d_in[3];
  const float* Wn     = (const float*)d_in[4];
  float* out          = (float*)d_out;

  unsigned* mx        = (unsigned*)d_ws;
  unsigned short* wqp = (unsigned short*)((char*)d_ws + 64);

  hipMemsetAsync(d_ws, 0, 64, stream);
  absmax_kernel<<<WQ_ELEMS / 4 / 256, 256, 0, stream>>>((const float4*)weight, mx);
  quant_kernel<<<WQ_ELEMS / 256, 256, 0, stream>>>(weight, Wp, Wn, mx, wqp);
  conv_kernel<<<dim3(32, HH / 2), 256, 0, stream>>>(x, wqp, bias, out);
}

// Round 11
// 322.925 us; speedup vs baseline: 1.4673x; 1.4673x over previous
//
#include <hip/hip_runtime.h>

#define CH 256
#define HH 56
#define WW 56
#define HWSZ 3136
#define WQ_ELEMS (CH*CH*9)      // 589824

#define XROW 2048               // shorts per input-row plane (64 iw * 32 ic)
#define XRGN 8192               // shorts per X region (4 rows)
#define WRGN 8192               // shorts per W region (one (tap, ic-chunk): 256 oc * 32 ic)

typedef short short8 __attribute__((ext_vector_type(8)));
typedef float f32x4 __attribute__((ext_vector_type(4)));
typedef __attribute__((address_space(3))) unsigned short as3_ushort;
typedef __attribute__((address_space(1))) const unsigned short as1_ushort;

__device__ __forceinline__ unsigned short f2bf(float f) {
  unsigned u = __builtin_bit_cast(unsigned, f);
  u += 0x7FFFu + ((u >> 16) & 1u);   // round-to-nearest-even
  return (unsigned short)(u >> 16);
}

// ---------------- kernel 1: max(|w|) ----------------
__global__ void absmax_kernel(const float4* __restrict__ w, unsigned* __restrict__ out) {
  int tid = blockIdx.x * 256 + threadIdx.x;
  float4 v = w[tid];
  float m = fmaxf(fmaxf(fabsf(v.x), fabsf(v.y)), fmaxf(fabsf(v.z), fabsf(v.w)));
  #pragma unroll
  for (int o = 32; o; o >>= 1) m = fmaxf(m, __shfl_xor(m, o, 64));
  if ((threadIdx.x & 63) == 0) atomicMax(out, __builtin_bit_cast(unsigned, m));
}

// ---------------- kernel 2: quantize -> bf16 (R6-verified layout) ----------------
// region (tap*8+t) of 8192 shorts; within: och*4096 + m*512 + l15*32 + kgp*8 + e,
// kgp = kg ^ ((l15>>2)&3)  (bank swizzle baked into global layout).
__global__ void quant_kernel(const float* __restrict__ w, const float* __restrict__ Wp,
                             const float* __restrict__ Wn, const unsigned* __restrict__ mx,
                             unsigned short* __restrict__ wq) {
  int o = blockIdx.x * 256 + threadIdx.x;
  int e   = o & 7;
  int kgp = (o >> 3) & 3;
  int l15 = (o >> 5) & 15;
  int m   = (o >> 9) & 7;
  int och = (o >> 12) & 1;
  int region = o >> 13;            // tap*8 + t
  int tap = region >> 3;
  int t   = region & 7;
  int kg  = kgp ^ ((l15 >> 2) & 3);
  int oc  = och * 128 + m * 16 + l15;
  int ic  = t * 32 + kg * 8 + e;
  float mv  = __builtin_bit_cast(float, *mx);
  float thr = 0.05f * mv;
  float v = w[(oc * CH + ic) * 9 + tap];
  float q = 0.f;
  if (mv > 0.f) {
    if (v > thr) q = Wp[0];
    else if (v < -thr) q = -Wn[0];
  }
  wq[o] = f2bf(q);
}

// ---------------- kernel 3: conv ----------------
// Block = (n, 2 output rows), 256 thr = 4 waves = 2 oc-halves x 2 rows.
// Wave tile 128oc x 64w (acc = 128 AGPR). LDS 64KB -> 2 independent blocks/CU:
// sibling block supplies latency-hiding TLP (m114). 72 steps of (tap, 32-ic).
// RACE FIX vs R10: every wave drains its own staging ops BEFORE the shared
// barrier (counted keeps for X); readers after the barrier are then safe.
__global__ __launch_bounds__(256, 2)
void conv_kernel(const float* __restrict__ x, const unsigned short* __restrict__ wq,
                 const float* __restrict__ bias, float* __restrict__ out) {
  extern __shared__ __align__(16) unsigned short lds[];
  unsigned short* Wl = lds;                 // 2 * WRGN shorts (32 KB)
  unsigned short* Xl = lds + 2 * WRGN;      // 2 * XRGN shorts (32 KB)

  const int tid  = threadIdx.x;
  const int lane = tid & 63;
  const int l15  = lane & 15;
  const int kg   = lane >> 4;      // 0..3 (ic octet)
  const int wid  = tid >> 6;       // 0..3
  const int och  = wid & 1;        // oc half (128 oc)
  const int wr   = wid >> 1;       // output row 0..1
  const int n    = blockIdx.x;
  const int h0   = blockIdx.y * 2;

  f32x4 acc[8][4];
  #pragma unroll
  for (int m = 0; m < 8; ++m)
    #pragma unroll
    for (int nc = 0; nc < 4; ++nc) acc[m][nc] = (f32x4)0.f;

  // ---- X staging geometry: 1024 chunks (r, iw, slot), 4/thread; iw fastest -> coalesced ----
  int goff[4], loff[4];
  bool ok[4];
  #pragma unroll
  for (int k = 0; k < 4; ++k) {
    int c    = tid + k * 256;
    int iw   = c & 63;
    int slot = (c >> 6) & 3;
    int r    = c >> 8;             // 0..3
    int hx = h0 + r - 1;
    int xw = iw - 1;
    ok[k] = ((unsigned)hx < (unsigned)HH) && ((unsigned)xw < (unsigned)WW);
    goff[k] = slot * 8 * HWSZ + (ok[k] ? (hx * WW + xw) : 0);
    loff[k] = r * XROW + iw * 32 + ((slot ^ ((iw >> 1) & 3)) * 8);
  }
  const float* xbase = x + (long)n * CH * HWSZ;

  // ---- B-read offsets (zero-conflict swizzle, measured R4) ----
  int boff[12];
  #pragma unroll
  for (int kw = 0; kw < 3; ++kw)
    #pragma unroll
    for (int nc = 0; nc < 4; ++nc) {
      int iw = nc * 16 + l15 + kw;
      if (iw > 63) iw = 63;        // feeds only discarded w >= 56
      boff[kw * 4 + nc] = iw * 32 + ((kg ^ ((iw >> 1) & 3)) * 8);
    }

  // ---- A-read offset (matches quant layout's baked swizzle) ----
  const int aoff = och * 4096 + l15 * 32 + ((kg ^ ((l15 >> 2) & 3)) * 8);

  // ---- W-stage: exactly 4 gload_lds per wave per step (16 x 1KB total) ----
  auto stageW = [&](int u) {
    const int tt = u / 9, tap = u - tt * 9;
    unsigned short* dstb = Wl + (u & 1) * WRGN;
    #pragma unroll
    for (int i = 0; i < 4; ++i) {
      const int g = i * 4 + wid;         // 0..15
      const unsigned short* src = wq + (tap * 8 + tt) * 8192 + g * 512 + lane * 8;
      __builtin_amdgcn_global_load_lds((as1_ushort*)src, (as3_ushort*)(dstb + g * 512), 16, 0, 0);
    }
  };

  float xr[4][8];
  // exactly 32 scalar loads per thread (deterministic vmcnt count)
  auto loadX = [&](int t1) {
    const int ic0 = t1 * 32;
    #pragma unroll
    for (int k = 0; k < 4; ++k)
      #pragma unroll
      for (int j = 0; j < 8; ++j)
        xr[k][j] = xbase[goff[k] + (ic0 + j) * HWSZ];
  };
  auto writeX = [&](int rb) {
    #pragma unroll
    for (int k = 0; k < 4; ++k) {
      short8 p;
      #pragma unroll
      for (int j = 0; j < 8; ++j) p[j] = ok[k] ? (short)f2bf(xr[k][j]) : (short)0;
      *(short8*)&Xl[rb + loff[k]] = p;
    }
  };

  // ---- prologue: X(0) [32 vm] then W(0) [4 vm]; ALL drains before barrier ----
  loadX(0);
  __builtin_amdgcn_sched_barrier(0);
  stageW(0);
  asm volatile("s_waitcnt vmcnt(4)" ::: "memory");    // X done (oldest 32), W(0) in flight
  writeX(0);
  asm volatile("s_waitcnt vmcnt(0) lgkmcnt(0)" ::: "memory");   // W(0) + ds_writes done
  __builtin_amdgcn_s_barrier();
  __builtin_amdgcn_sched_barrier(0);

  for (int t = 0; t < 8; ++t) {
    const int xrb = (t & 1) * XRGN;
    #pragma unroll
    for (int tap = 0; tap < 9; ++tap) {
      const int u = t * 9 + tap;

      // stage next W region; at tap 7 also issue next X chunk's loads (after the stage)
      if (u < 71) stageW(u + 1);
      if (tap == 7 && t < 7) { __builtin_amdgcn_sched_barrier(0); loadX(t + 1); }

      // ---- compute: one tap, K=32; W(u) was drained before the previous barrier ----
      const int kh = tap / 3, kw = tap - kh * 3;
      const unsigned short* ap = Wl + (u & 1) * WRGN + aoff;
      const int rxo = xrb + (wr + kh) * XROW;
      short8 b[4];
      #pragma unroll
      for (int nc = 0; nc < 4; ++nc) b[nc] = *(const short8*)&Xl[rxo + boff[kw * 4 + nc]];
      short8 a[8];
      #pragma unroll
      for (int m = 0; m < 8; ++m) a[m] = *(const short8*)(ap + m * 512);
      __builtin_amdgcn_s_setprio(1);
      #pragma unroll
      for (int m = 0; m < 8; ++m)
        #pragma unroll
        for (int nc = 0; nc < 4; ++nc)
          acc[m][nc] = __builtin_amdgcn_mfma_f32_16x16x32_bf16(a[m], b[nc], acc[m][nc], 0, 0, 0);
      __builtin_amdgcn_s_setprio(0);

      // ---- exit waits: drain own staging BEFORE the shared barrier ----
      if (tap == 7 && t < 7) {
        // queue: [W'(4), X(32)] -> drain W', keep X in flight across the barrier
        asm volatile("s_waitcnt vmcnt(32)" ::: "memory");
      } else if (tap == 8 && t < 7) {
        // queue: [X(32), W'(4)] -> drain X, write it, then drain W' + ds_writes
        asm volatile("s_waitcnt vmcnt(4)" ::: "memory");
        writeX(XRGN - xrb);
        asm volatile("s_waitcnt vmcnt(0) lgkmcnt(0)" ::: "memory");
      } else {
        asm volatile("s_waitcnt vmcnt(0)" ::: "memory");          // W' done
      }
      __builtin_amdgcn_s_barrier();
      __builtin_amdgcn_sched_barrier(0);
    }
  }

  // ---- epilogue: D col = l15 (w), row = kg*4 + j (oc) ----
  const int h = h0 + wr;
  #pragma unroll
  for (int m = 0; m < 8; ++m) {
    const int ocb = och * 128 + m * 16 + kg * 4;
    #pragma unroll
    for (int nc = 0; nc < 4; ++nc) {
      const int w = nc * 16 + l15;
      if (w < WW) {
        float* op = out + ((long)(n * CH + ocb) * HH + h) * WW + w;
        #pragma unroll
        for (int j = 0; j < 4; ++j)
          op[(long)j * HWSZ] = acc[m][nc][j] + bias[ocb + j];
      }
    }
  }
}

extern "C" void kernel_launch(void* const* d_in, const int* in_sizes, int n_in,
                              void* d_out, int out_size, void* d_ws, size_t ws_size,
                              hipStream_t stream) {
  const float* x      = (const float*)d_in[0];
  const float* weight = (const float*)d_in[1];
  const float* bias   = (const float*)d_in[2];
  const float* Wp     = (const float*)d_in[3];
  const float* Wn     = (const float*)d_in[4];
  float* out          = (float*)d_out;

  unsigned* mx        = (unsigned*)d_ws;
  unsigned short* wqp = (unsigned short*)((char*)d_ws + 64);

  static const int LDS_BYTES = (2 * WRGN + 2 * XRGN) * 2;   // 65536
  hipFuncSetAttribute((const void*)conv_kernel,
                      hipFuncAttributeMaxDynamicSharedMemorySize, LDS_BYTES);

  hipMemsetAsync(d_ws, 0, 64, stream);
  absmax_kernel<<<WQ_ELEMS / 4 / 256, 256, 0, stream>>>((const float4*)weight, mx);
  quant_kernel<<<WQ_ELEMS / 256, 256, 0, stream>>>(weight, Wp, Wn, mx, wqp);
  conv_kernel<<<dim3(32, HH / 2), 256, LDS_BYTES, stream>>>(x, wqp, bias, out);
}

// Round 12
// 276.954 us; speedup vs baseline: 1.7108x; 1.1660x over previous
//
#include <hip/hip_runtime.h>

#define CH 256
#define HH 56
#define WW 56
#define HWSZ 3136
#define WQ_ELEMS (CH*CH*9)      // 589824

#define XRGN 8192               // shorts per X region (4 rows x 64 iw x 32 ic)
#define WRGN 8192               // shorts per W region (one (tap, ic-chunk): 256 oc x 32 ic)
#define XT_OFF 2097152          // byte offset of x_t in ws
#define HP 58                   // padded h (rows 0 and 57 zero)

typedef short short8 __attribute__((ext_vector_type(8)));
typedef float f32x4 __attribute__((ext_vector_type(4)));
typedef __attribute__((address_space(3))) unsigned short as3_ushort;
typedef __attribute__((address_space(1))) const unsigned short as1_ushort;

__device__ __forceinline__ unsigned short f2bf(float f) {
  unsigned u = __builtin_bit_cast(unsigned, f);
  u += 0x7FFFu + ((u >> 16) & 1u);   // round-to-nearest-even
  return (unsigned short)(u >> 16);
}

// ---------------- kernel 1: max(|w|) ----------------
__global__ void absmax_kernel(const float4* __restrict__ w, unsigned* __restrict__ out) {
  int tid = blockIdx.x * 256 + threadIdx.x;
  float4 v = w[tid];
  float m = fmaxf(fmaxf(fabsf(v.x), fabsf(v.y)), fmaxf(fabsf(v.z), fabsf(v.w)));
  #pragma unroll
  for (int o = 32; o; o >>= 1) m = fmaxf(m, __shfl_xor(m, o, 64));
  if ((threadIdx.x & 63) == 0) atomicMax(out, __builtin_bit_cast(unsigned, m));
}

// ---------------- kernel 2: quantize -> bf16 (R6-verified layout, unchanged) ----------------
// region (tap*8+t) of 8192 shorts; within: och*4096 + m*512 + l15*32 + kgp*8 + e,
// kgp = kg ^ ((l15>>2)&3)  (A bank swizzle baked into global layout).
__global__ void quant_kernel(const float* __restrict__ w, const float* __restrict__ Wp,
                             const float* __restrict__ Wn, const unsigned* __restrict__ mx,
                             unsigned short* __restrict__ wq) {
  int o = blockIdx.x * 256 + threadIdx.x;
  int e   = o & 7;
  int kgp = (o >> 3) & 3;
  int l15 = (o >> 5) & 15;
  int m   = (o >> 9) & 7;
  int och = (o >> 12) & 1;
  int region = o >> 13;            // tap*8 + t
  int tap = region >> 3;
  int t   = region & 7;
  int kg  = kgp ^ ((l15 >> 2) & 3);
  int oc  = och * 128 + m * 16 + l15;
  int ic  = t * 32 + kg * 8 + e;
  float mv  = __builtin_bit_cast(float, *mx);
  float thr = 0.05f * mv;
  float v = w[(oc * CH + ic) * 9 + tap];
  float q = 0.f;
  if (mv > 0.f) {
    if (v > thr) q = Wp[0];
    else if (v < -thr) q = -Wn[0];
  }
  wq[o] = f2bf(q);
}

// ---------------- kernel 3: x -> x_t bf16 [n][58 hp][64 iw][256 icp] ----------------
// Zero-padded halo baked in; B bank swizzle baked into icp ordering:
// icp = chunk*32 + (kg ^ ((iw>>1)&3))*8 + e. Reads coalesced along w.
__global__ __launch_bounds__(256)
void xpose_kernel(const float* __restrict__ x, unsigned short* __restrict__ xt) {
  const int n = blockIdx.x, hp = blockIdx.y;
  const int hx = hp - 1;
  unsigned short* plane = xt + ((long)n * HP + hp) * (64 * 256);
  const int tid = threadIdx.x;
  const int iw  = tid & 63;
  const int su  = tid >> 6;        // 0..3
  const int xw  = iw - 1;
  const bool wok = ((unsigned)hx < (unsigned)HH) && ((unsigned)xw < (unsigned)WW);
  const int hxc = wok ? hx : 0, xwc = wok ? xw : 0;
  const float* xsrc = x + (long)n * CH * HWSZ + (long)hxc * WW + xwc;
  const int s = (iw >> 1) & 3;
  #pragma unroll
  for (int s2 = 0; s2 < 8; ++s2) {
    const int slot = su * 8 + s2;    // 0..31 (8 global ic each)
    short8 p;
    #pragma unroll
    for (int e = 0; e < 8; ++e) {
      float v = wok ? xsrc[(long)(slot * 8 + e) * HWSZ] : 0.f;
      p[e] = (short)f2bf(v);
    }
    const int icp = (slot >> 2) * 32 + ((slot & 3) ^ s) * 8;
    *(short8*)&plane[iw * 256 + icp] = p;
  }
}

// ---------------- kernel 4: conv ----------------
// Block = (n, 2 output rows), 256 thr = 4 waves = 2 oc-halves x 2 rows.
// Wave tile 128oc x 64w (acc = 128 AGPR). LDS 64KB -> 2 independent blocks/CU
// (sibling-block TLP, m114). ALL staging via global_load_lds (W tap-ring 2x16KB,
// X per-ic-chunk dbuf 2x16KB) -> no staging registers, no ds_writes, no f2bf.
// Race-free: every wave drains its own staging ops before each shared barrier.
__global__ __launch_bounds__(256, 2)
void conv_kernel(const unsigned short* __restrict__ xt, const unsigned short* __restrict__ wq,
                 const float* __restrict__ bias, float* __restrict__ out) {
  extern __shared__ __align__(16) unsigned short lds[];
  unsigned short* Wl = lds;                 // 2 * WRGN shorts (32 KB)
  unsigned short* Xl = lds + 2 * WRGN;      // 2 * XRGN shorts (32 KB)

  const int tid  = threadIdx.x;
  const int lane = tid & 63;
  const int l15  = lane & 15;
  const int kg   = lane >> 4;      // 0..3 (ic octet)
  const int wid  = tid >> 6;       // 0..3
  const int och  = wid & 1;        // oc half (128 oc)
  const int wr   = wid >> 1;       // output row 0..1
  const int n    = blockIdx.x;
  const int h0   = blockIdx.y * 2;

  f32x4 acc[8][4];
  #pragma unroll
  for (int m = 0; m < 8; ++m)
    #pragma unroll
    for (int nc = 0; nc < 4; ++nc) acc[m][nc] = (f32x4)0.f;

  // ---- B-read offsets (swizzle matches x_t's baked icp ordering) ----
  int boff[12];
  #pragma unroll
  for (int kw = 0; kw < 3; ++kw)
    #pragma unroll
    for (int nc = 0; nc < 4; ++nc) {
      int iw = nc * 16 + l15 + kw;
      if (iw > 63) iw = 63;        // feeds only discarded w >= 56 (row 63 is zeros anyway)
      boff[kw * 4 + nc] = iw * 32 + ((kg ^ ((iw >> 1) & 3)) * 8);
    }

  // ---- A-read offset (matches quant layout's baked swizzle) ----
  const int aoff = och * 4096 + l15 * 32 + ((kg ^ ((l15 >> 2) & 3)) * 8);

  // ---- W-stage: exactly 4 gload_lds per wave per step (16 x 1KB total) ----
  auto stageW = [&](int u) {
    const int tt = u / 9, tap = u - tt * 9;
    unsigned short* dstb = Wl + (u & 1) * WRGN;
    #pragma unroll
    for (int i = 0; i < 4; ++i) {
      const int g = i * 4 + wid;         // 0..15
      const unsigned short* src = wq + (tap * 8 + tt) * 8192 + g * 512 + lane * 8;
      __builtin_amdgcn_global_load_lds((as1_ushort*)src, (as3_ushort*)(dstb + g * 512), 16, 0, 0);
    }
  };

  // ---- X-stage: wave wid stages input row (h0+wid); 4 gload_lds per wave ----
  // src: x_t plane row slice [iw][t*32 .. t*32+32) icp; per lane: iw = i*16+(l>>2),
  // 16B quarter (l&3). dst: linear [r][iw][32ic] (uniform base + lane*16 by HW).
  const unsigned short* xplane = xt + ((long)n * HP + h0 + wid) * (64 * 256);
  const int xsrc_lane = ((lane >> 2) * 256) + (lane & 3) * 8;
  auto stageX = [&](int t1) {
    const unsigned short* pl = xplane + t1 * 32 + xsrc_lane;
    unsigned short* dstb = Xl + (t1 & 1) * XRGN + wid * 2048;
    #pragma unroll
    for (int i = 0; i < 4; ++i) {
      __builtin_amdgcn_global_load_lds((as1_ushort*)(pl + i * 16 * 256),
                                       (as3_ushort*)(dstb + i * 512), 16, 0, 0);
    }
  };

  // ---- prologue: X(0) + W(0); drain all own ops, barrier ----
  stageX(0);
  stageW(0);
  asm volatile("s_waitcnt vmcnt(0)" ::: "memory");
  __builtin_amdgcn_s_barrier();
  __builtin_amdgcn_sched_barrier(0);

  for (int t = 0; t < 8; ++t) {
    const int xcur = (t & 1) * XRGN;
    #pragma unroll
    for (int tap = 0; tap < 9; ++tap) {
      const int u = t * 9 + tap;

      // stage next W region; at tap 7 also stage next X chunk (issued after W')
      if (u < 71) stageW(u + 1);
      if (tap == 7 && t < 7) stageX(t + 1);

      // ---- compute: one tap, K=32 (W(u), X(t) drained before previous barrier) ----
      const int kh = tap / 3, kw = tap - kh * 3;
      const unsigned short* ap = Wl + (u & 1) * WRGN + aoff;
      const int rxo = xcur + (wr + kh) * 2048;
      short8 b[4];
      #pragma unroll
      for (int nc = 0; nc < 4; ++nc) b[nc] = *(const short8*)&Xl[rxo + boff[kw * 4 + nc]];
      short8 a[8];
      #pragma unroll
      for (int m = 0; m < 8; ++m) a[m] = *(const short8*)(ap + m * 512);
      __builtin_amdgcn_s_setprio(1);
      #pragma unroll
      for (int m = 0; m < 8; ++m)
        #pragma unroll
        for (int nc = 0; nc < 4; ++nc)
          acc[m][nc] = __builtin_amdgcn_mfma_f32_16x16x32_bf16(a[m], b[nc], acc[m][nc], 0, 0, 0);
      __builtin_amdgcn_s_setprio(0);

      // ---- exit waits: drain own staging BEFORE the shared barrier ----
      if (tap == 7 && t < 7) {
        // queue: [W'(4), X(4)] -> drain W', keep X in flight across one barrier
        asm volatile("s_waitcnt vmcnt(4)" ::: "memory");
      } else {
        // drains W' (and at tap 8 also the X staged at tap 7)
        asm volatile("s_waitcnt vmcnt(0)" ::: "memory");
      }
      __builtin_amdgcn_s_barrier();
      __builtin_amdgcn_sched_barrier(0);
    }
  }

  // ---- epilogue: D col = l15 (w), row = kg*4 + j (oc) ----
  const int h = h0 + wr;
  #pragma unroll
  for (int m = 0; m < 8; ++m) {
    const int ocb = och * 128 + m * 16 + kg * 4;
    #pragma unroll
    for (int nc = 0; nc < 4; ++nc) {
      const int w = nc * 16 + l15;
      if (w < WW) {
        float* op = out + ((long)(n * CH + ocb) * HH + h) * WW + w;
        #pragma unroll
        for (int j = 0; j < 4; ++j)
          op[(long)j * HWSZ] = acc[m][nc][j] + bias[ocb + j];
      }
    }
  }
}

extern "C" void kernel_launch(void* const* d_in, const int* in_sizes, int n_in,
                              void* d_out, int out_size, void* d_ws, size_t ws_size,
                              hipStream_t stream) {
  const float* x      = (const float*)d_in[0];
  const float* weight = (const float*)d_in[1];
  const float* bias   = (const float*)d_in[2];
  const float* Wp     = (const float*)d_in[3];
  const float* Wn     = (const float*)d_in[4];
  float* out          = (float*)d_out;

  unsigned* mx        = (unsigned*)d_ws;
  unsigned short* wqp = (unsigned short*)((char*)d_ws + 64);
  unsigned short* xtp = (unsigned short*)((char*)d_ws + XT_OFF);   // 60.8 MB

  static const int LDS_BYTES = (2 * WRGN + 2 * XRGN) * 2;   // 65536
  hipFuncSetAttribute((const void*)conv_kernel,
                      hipFuncAttributeMaxDynamicSharedMemorySize, LDS_BYTES);

  hipMemsetAsync(d_ws, 0, 64, stream);
  absmax_kernel<<<WQ_ELEMS / 4 / 256, 256, 0, stream>>>((const float4*)weight, mx);
  quant_kernel<<<WQ_ELEMS / 256, 256, 0, stream>>>(weight, Wp, Wn, mx, wqp);
  xpose_kernel<<<dim3(32, HP), 256, 0, stream>>>(x, xtp);
  conv_kernel<<<dim3(32, HH / 2), 256, LDS_BYTES, stream>>>(xtp, wqp, bias, out);
}

// Round 13
// 263.346 us; speedup vs baseline: 1.7992x; 1.0517x over previous
//
#include <hip/hip_runtime.h>

#define CH 256
#define HH 56
#define WW 56
#define HWSZ 3136
#define WQ_ELEMS (CH*CH*9)      // 589824

#define XRGN 8192               // shorts: single X buffer (4 rows x 64 iw x 32 ic)
#define WRGN 8192               // shorts per W region (one (tap, ic-chunk): 256 oc x 32 ic)
#define XT_OFF 2097152          // byte offset of x_t in ws
#define HP 58                   // padded h (rows 0 and 57 zero)

typedef short short8 __attribute__((ext_vector_type(8)));
typedef float f32x4 __attribute__((ext_vector_type(4)));
typedef __attribute__((address_space(3))) unsigned short as3_ushort;
typedef __attribute__((address_space(1))) const unsigned short as1_ushort;

__device__ __forceinline__ unsigned short f2bf(float f) {
  unsigned u = __builtin_bit_cast(unsigned, f);
  u += 0x7FFFu + ((u >> 16) & 1u);   // round-to-nearest-even
  return (unsigned short)(u >> 16);
}

// ---------------- kernel 1: max(|w|) ----------------
__global__ void absmax_kernel(const float4* __restrict__ w, unsigned* __restrict__ out) {
  int tid = blockIdx.x * 256 + threadIdx.x;
  float4 v = w[tid];
  float m = fmaxf(fmaxf(fabsf(v.x), fabsf(v.y)), fmaxf(fabsf(v.z), fabsf(v.w)));
  #pragma unroll
  for (int o = 32; o; o >>= 1) m = fmaxf(m, __shfl_xor(m, o, 64));
  if ((threadIdx.x & 63) == 0) atomicMax(out, __builtin_bit_cast(unsigned, m));
}

// ---------------- kernel 2: quantize -> bf16 (verified layout, unchanged from R12) ----------------
__global__ void quant_kernel(const float* __restrict__ w, const float* __restrict__ Wp,
                             const float* __restrict__ Wn, const unsigned* __restrict__ mx,
                             unsigned short* __restrict__ wq) {
  int o = blockIdx.x * 256 + threadIdx.x;
  int e   = o & 7;
  int kgp = (o >> 3) & 3;
  int l15 = (o >> 5) & 15;
  int m   = (o >> 9) & 7;
  int och = (o >> 12) & 1;
  int region = o >> 13;            // tap*8 + t
  int tap = region >> 3;
  int t   = region & 7;
  int kg  = kgp ^ ((l15 >> 2) & 3);
  int oc  = och * 128 + m * 16 + l15;
  int ic  = t * 32 + kg * 8 + e;
  float mv  = __builtin_bit_cast(float, *mx);
  float thr = 0.05f * mv;
  float v = w[(oc * CH + ic) * 9 + tap];
  float q = 0.f;
  if (mv > 0.f) {
    if (v > thr) q = Wp[0];
    else if (v < -thr) q = -Wn[0];
  }
  wq[o] = f2bf(q);
}

// ---------------- kernel 3: x -> x_t bf16 [n][58][64 iw][256 icp] (unchanged from R12) ----------------
__global__ __launch_bounds__(256)
void xpose_kernel(const float* __restrict__ x, unsigned short* __restrict__ xt) {
  const int n = blockIdx.x, hp = blockIdx.y;
  const int hx = hp - 1;
  unsigned short* plane = xt + ((long)n * HP + hp) * (64 * 256);
  const int tid = threadIdx.x;
  const int iw  = tid & 63;
  const int su  = tid >> 6;        // 0..3
  const int xw  = iw - 1;
  const bool wok = ((unsigned)hx < (unsigned)HH) && ((unsigned)xw < (unsigned)WW);
  const int hxc = wok ? hx : 0, xwc = wok ? xw : 0;
  const float* xsrc = x + (long)n * CH * HWSZ + (long)hxc * WW + xwc;
  const int s = (iw >> 1) & 3;
  #pragma unroll
  for (int s2 = 0; s2 < 8; ++s2) {
    const int slot = su * 8 + s2;    // 0..31
    short8 p;
    #pragma unroll
    for (int e = 0; e < 8; ++e) {
      float v = wok ? xsrc[(long)(slot * 8 + e) * HWSZ] : 0.f;
      p[e] = (short)f2bf(v);
    }
    const int icp = (slot >> 2) * 32 + ((slot & 3) ^ s) * 8;
    *(short8*)&plane[iw * 256 + icp] = p;
  }
}

// ---------------- kernel 4: conv, cross-step A-prefetch into same regs ----------------
// Block = (n, 2 rows), 256 thr = 4 waves (2 och x 2 wr); wave tile 128oc x 64w.
// LDS 64KB (W 3-region ring 48KB + X single 16KB) -> 2 blocks/CU guaranteed.
// Per step: stageW(u+2) async; b[4] in-step; MFMA uses a[8] read LAST step
// (region index tap%3 is compile-time since 9 % 3 == 0); post-cluster re-read
// a[8] from region (tap+1)%3 (WAR-safe: MFMAs latch operands at issue).
__global__ __launch_bounds__(256, 2)
void conv_kernel(const unsigned short* __restrict__ xt, const unsigned short* __restrict__ wq,
                 const float* __restrict__ bias, float* __restrict__ out) {
  extern __shared__ __align__(16) unsigned short lds[];
  unsigned short* Wl = lds;                 // 3 * WRGN shorts (48 KB)
  unsigned short* Xl = lds + 3 * WRGN;      // XRGN shorts (16 KB)

  const int tid  = threadIdx.x;
  const int lane = tid & 63;
  const int l15  = lane & 15;
  const int kg   = lane >> 4;
  const int wid  = tid >> 6;       // 0..3
  const int och  = wid & 1;
  const int wr   = wid >> 1;
  const int n    = blockIdx.x;
  const int h0   = blockIdx.y * 2;

  f32x4 acc[8][4];
  #pragma unroll
  for (int m = 0; m < 8; ++m)
    #pragma unroll
    for (int nc = 0; nc < 4; ++nc) acc[m][nc] = (f32x4)0.f;

  // ---- B-read offsets (swizzle matches x_t's baked icp ordering) ----
  int boff[12];
  #pragma unroll
  for (int kw = 0; kw < 3; ++kw)
    #pragma unroll
    for (int nc = 0; nc < 4; ++nc) {
      int iw = nc * 16 + l15 + kw;
      if (iw > 63) iw = 63;        // feeds only discarded w >= 56
      boff[kw * 4 + nc] = iw * 32 + ((kg ^ ((iw >> 1) & 3)) * 8);
    }

  // ---- A-read offset (matches quant layout's baked swizzle) ----
  const int aoff = och * 4096 + l15 * 32 + ((kg ^ ((l15 >> 2) & 3)) * 8);

  // ---- W-stage into region rgn, data (tap', t'): 4 gload_lds/wave ----
  auto stageW = [&](int rgn, int tapp, int tt) {
    unsigned short* dstb = Wl + rgn * WRGN;
    #pragma unroll
    for (int i = 0; i < 4; ++i) {
      const int g = i * 4 + wid;         // 0..15
      const unsigned short* src = wq + (tapp * 8 + tt) * 8192 + g * 512 + lane * 8;
      __builtin_amdgcn_global_load_lds((as1_ushort*)src, (as3_ushort*)(dstb + g * 512), 16, 0, 0);
    }
  };

  // ---- X-stage: wave wid stages input row (h0+wid); 4 gload_lds/wave ----
  const unsigned short* xplane = xt + ((long)n * HP + h0 + wid) * (64 * 256);
  const int xsrc_lane = ((lane >> 2) * 256) + (lane & 3) * 8;
  auto stageX = [&](int t1) {
    const unsigned short* pl = xplane + t1 * 32 + xsrc_lane;
    unsigned short* dstb = Xl + wid * 2048;
    #pragma unroll
    for (int i = 0; i < 4; ++i) {
      __builtin_amdgcn_global_load_lds((as1_ushort*)(pl + i * 16 * 256),
                                       (as3_ushort*)(dstb + i * 512), 16, 0, 0);
    }
  };

  short8 a[8];
  auto readA = [&](int rgn) {
    const unsigned short* ap = Wl + rgn * WRGN + aoff;
    #pragma unroll
    for (int m = 0; m < 8; ++m) a[m] = *(const short8*)(ap + m * 512);
  };

  // ---- prologue: X(0), W regions 0,1 (steps 0,1); drain; preload a for step 0 ----
  stageX(0);
  stageW(0, 0, 0);
  stageW(1, 1, 0);
  asm volatile("s_waitcnt vmcnt(0)" ::: "memory");
  __builtin_amdgcn_s_barrier();
  __builtin_amdgcn_sched_barrier(0);
  readA(0);

  for (int t = 0; t < 8; ++t) {
    #pragma unroll
    for (int tap = 0; tap < 9; ++tap) {
      // ---- stage W for step u+2 into region (tap+2)%3 (compile-time) ----
      if (tap <= 6)      stageW((tap + 2) % 3, tap + 2, t);
      else if (t < 7)    stageW((tap + 2) % 3, tap - 7, t + 1);

      // ---- b reads for this tap ----
      const int kh = tap / 3, kw = tap - kh * 3;
      const int rxo = (wr + kh) * 2048;
      short8 b[4];
      #pragma unroll
      for (int nc = 0; nc < 4; ++nc) b[nc] = *(const short8*)&Xl[rxo + boff[kw * 4 + nc]];
      __builtin_amdgcn_sched_barrier(0);

      // ---- MFMA cluster (a landed last step; waits lgkm for b only) ----
      __builtin_amdgcn_s_setprio(1);
      #pragma unroll
      for (int m = 0; m < 8; ++m)
        #pragma unroll
        for (int nc = 0; nc < 4; ++nc)
          acc[m][nc] = __builtin_amdgcn_mfma_f32_16x16x32_bf16(a[m], b[nc], acc[m][nc], 0, 0, 0);
      __builtin_amdgcn_s_setprio(0);
      __builtin_amdgcn_sched_barrier(0);

      // ---- prefetch a for step u+1 from region (tap+1)%3 (overlaps drain/barrier) ----
      readA((tap + 1) % 3);

      // ---- drain own W-stage ops, then shared barrier ----
      asm volatile("s_waitcnt vmcnt(0)" ::: "memory");
      __builtin_amdgcn_s_barrier();
      __builtin_amdgcn_sched_barrier(0);
    }

    // ---- chunk boundary: restage X (single buffer) behind its own barrier ----
    if (t < 7) {
      stageX(t + 1);
      asm volatile("s_waitcnt vmcnt(0)" ::: "memory");
      __builtin_amdgcn_s_barrier();
      __builtin_amdgcn_sched_barrier(0);
    }
  }

  // ---- epilogue: D col = l15 (w), row = kg*4 + j (oc) ----
  const int h = h0 + wr;
  #pragma unroll
  for (int m = 0; m < 8; ++m) {
    const int ocb = och * 128 + m * 16 + kg * 4;
    #pragma unroll
    for (int nc = 0; nc < 4; ++nc) {
      const int w = nc * 16 + l15;
      if (w < WW) {
        float* op = out + ((long)(n * CH + ocb) * HH + h) * WW + w;
        #pragma unroll
        for (int j = 0; j < 4; ++j)
          op[(long)j * HWSZ] = acc[m][nc][j] + bias[ocb + j];
      }
    }
  }
}

extern "C" void kernel_launch(void* const* d_in, const int* in_sizes, int n_in,
                              void* d_out, int out_size, void* d_ws, size_t ws_size,
                              hipStream_t stream) {
  const float* x      = (const float*)d_in[0];
  const float* weight = (const float*)d_in[1];
  const float* bias   = (const float*)d_in[2];
  const float* Wp     = (const float*)d_in[3];
  const float* Wn     = (const float*)d_in[4];
  float* out          = (float*)d_out;

  unsigned* mx        = (unsigned*)d_ws;
  unsigned short* wqp = (unsigned short*)((char*)d_ws + 64);
  unsigned short* xtp = (unsigned short*)((char*)d_ws + XT_OFF);

  static const int LDS_BYTES = (3 * WRGN + XRGN) * 2;   // 65536
  hipFuncSetAttribute((const void*)conv_kernel,
                      hipFuncAttributeMaxDynamicSharedMemorySize, LDS_BYTES);

  hipMemsetAsync(d_ws, 0, 64, stream);
  absmax_kernel<<<WQ_ELEMS / 4 / 256, 256, 0, stream>>>((const float4*)weight, mx);
  quant_kernel<<<WQ_ELEMS / 256, 256, 0, stream>>>(weight, Wp, Wn, mx, wqp);
  xpose_kernel<<<dim3(32, HP), 256, 0, stream>>>(x, xtp);
  conv_kernel<<<dim3(32, HH / 2), 256, LDS_BYTES, stream>>>(xtp, wqp, bias, out);
}